// Round 1
// baseline (762.625 us; speedup 1.0000x reference)
//
#include <hip/hip_runtime.h>
#include <hip/hip_bf16.h>

#define B_ 16
#define T_ 4096
#define HKV_ 8
#define HD_ 128
#define DM_ 4096
#define HQ_ 32
#define G_ 4
#define CHUNK_ 64
#define TOPK_ 16
#define WINDOW_ 512
#define NC_ 64
#define EPS_ 1e-6f

#define SPLITK 32
#define KCH (DM_ / SPLITK)   // 128

// ---------------- GEMM: C[16,4096] += A[16,4096] @ W[4096,4096] (+bias on y==0) ----------------
__global__ __launch_bounds__(256) void gemm16_splitk(
    const float* __restrict__ A, const float* __restrict__ W,
    const float* __restrict__ bias, float* __restrict__ C)
{
  int n = blockIdx.x * 256 + threadIdx.x;
  int k0 = blockIdx.y * KCH;
  float acc[B_];
  if (blockIdx.y == 0) {
    float bv = bias[n];
#pragma unroll
    for (int b = 0; b < B_; b++) acc[b] = bv;
  } else {
#pragma unroll
    for (int b = 0; b < B_; b++) acc[b] = 0.f;
  }
  const float* Wp = W + (size_t)k0 * DM_ + n;
  for (int kk = 0; kk < KCH; kk++) {
    float w = Wp[(size_t)kk * DM_];
#pragma unroll
    for (int b = 0; b < B_; b++) acc[b] += A[b * DM_ + k0 + kk] * w;
  }
#pragma unroll
  for (int b = 0; b < B_; b++) atomicAdd(&C[b * DM_ + n], acc[b]);
}

// ---------------- landmarks + scores + top-16 + chunk weights ----------------
// grid: B*HKV blocks, 256 threads (4 waves = 4 GQA heads)
__global__ __launch_bounds__(256) void lmk_topk_kernel(
    const float* __restrict__ q_raw, const float* __restrict__ k_cache,
    const float* __restrict__ lse_swa, const float* __restrict__ qn_w,
    const float* __restrict__ lmkn_w, const int* __restrict__ seq_lens,
    float* __restrict__ q_norm, float* __restrict__ cw_ws, int* __restrict__ idx_ws)
{
  int blk = blockIdx.x;
  int b = blk / HKV_, kv = blk % HKV_;
  int tid = threadIdx.x;
  int w = tid >> 6, lane = tid & 63;
  int qh = kv * G_ + w;

  __shared__ float qs[G_][HD_];
  __shared__ float sS[G_][NC_];

  // q RMSNorm: one wave per q head
  {
    int d0 = lane * 2;
    const float* qp = q_raw + ((size_t)b * HQ_ + qh) * HD_;
    float v0 = qp[d0], v1 = qp[d0 + 1];
    float ss = v0 * v0 + v1 * v1;
#pragma unroll
    for (int off = 1; off < 64; off <<= 1) ss += __shfl_xor(ss, off);
    float rs = rsqrtf(ss * (1.0f / HD_) + EPS_);
    float n0 = v0 * rs * qn_w[d0], n1 = v1 * rs * qn_w[d0 + 1];
    qs[w][d0] = n0; qs[w][d0 + 1] = n1;
    float* qo = q_norm + ((size_t)b * HQ_ + qh) * HD_;
    qo[d0] = n0; qo[d0 + 1] = n1;
  }
  __syncthreads();

  const float scale = 0.088388347648318447f;  // 1/sqrt(128)

  // landmark RMSNorm + scores vs the 4 q heads; each wave handles 16 landmarks
  for (int c = w; c < NC_; c += 4) {
    int d0 = lane * 2;
    const float* kp = k_cache + (((size_t)b * T_ + c * CHUNK_) * HKV_ + kv) * HD_;
    float v0 = kp[d0], v1 = kp[d0 + 1];
    float ss = v0 * v0 + v1 * v1;
#pragma unroll
    for (int off = 1; off < 64; off <<= 1) ss += __shfl_xor(ss, off);
    float rs = rsqrtf(ss * (1.0f / HD_) + EPS_);
    float l0 = v0 * rs * lmkn_w[d0], l1 = v1 * rs * lmkn_w[d0 + 1];
#pragma unroll
    for (int gi = 0; gi < G_; gi++) {
      float p = l0 * qs[gi][d0] + l1 * qs[gi][d0 + 1];
#pragma unroll
      for (int off = 1; off < 64; off <<= 1) p += __shfl_xor(p, off);
      if (lane == 0) sS[gi][c] = p * scale;
    }
  }
  __syncthreads();

  // validity + top-16 + softmax([scores, lse]); wave w handles head w
  {
    int sl = seq_lens[b];
    int cs = lane * CHUNK_;
    float s = sS[w][lane];
    bool valid = (cs + CHUNK_ <= sl) && (cs < sl - WINDOW_);
    if (!valid) s = -1e9f;

    float topv[TOPK_]; int topi[TOPK_];
    float cur = s;
    for (int j = 0; j < TOPK_; j++) {
      float v = cur; int ix = lane;
#pragma unroll
      for (int off = 1; off < 64; off <<= 1) {
        float ov = __shfl_xor(v, off);
        int oi = __shfl_xor(ix, off);
        if (ov > v || (ov == v && oi < ix)) { v = ov; ix = oi; }
      }
      topv[j] = v; topi[j] = ix;
      if (lane == ix) cur = -INFINITY;
    }

    float lse = lse_swa[b * HQ_ + qh];
    float m = lse;
#pragma unroll
    for (int j = 0; j < TOPK_; j++) m = fmaxf(m, topv[j]);
    float sum = expf(lse - m);
    float e[TOPK_];
#pragma unroll
    for (int j = 0; j < TOPK_; j++) { e[j] = expf(topv[j] - m); sum += e[j]; }
    float inv = 1.0f / sum;
    if (lane == 0) {
      float* cwp = cw_ws + ((size_t)b * HQ_ + qh) * (TOPK_ + 1);
      int* ip = idx_ws + ((size_t)b * HQ_ + qh) * TOPK_;
#pragma unroll
      for (int j = 0; j < TOPK_; j++) { cwp[j] = e[j] * inv; ip[j] = topi[j]; }
      cwp[TOPK_] = expf(lse - m) * inv;
    }
  }
}

// ---------------- gathered per-chunk softmax attention ----------------
// grid: B*HQ blocks, 256 threads
__global__ __launch_bounds__(256) void attn_kernel(
    const float* __restrict__ q_norm, const float* __restrict__ k_cache,
    const float* __restrict__ v_cache, const float* __restrict__ cw_ws,
    const int* __restrict__ idx_ws, float* __restrict__ o_mid)
{
  int bh = blockIdx.x;
  int b = bh >> 5, h = bh & 31;
  int kvh = h >> 2;
  int tid = threadIdx.x;

  __shared__ float qs[HD_];
  __shared__ float pS[CHUNK_];
  __shared__ float accS[HD_];

  if (tid < HD_) qs[tid] = q_norm[(size_t)bh * HD_ + tid];
  __syncthreads();

  const float scale = 0.088388347648318447f;
  const float* cwp = cw_ws + (size_t)bh * (TOPK_ + 1);
  const int* ip = idx_ws + (size_t)bh * TOPK_;

  int t = tid >> 2, q4 = tid & 3;     // score phase: 64 tokens x 4 dim-quarters
  int d = tid & 127, tp = tid >> 7;   // PV phase: 128 dims x 2 token halves
  float acc = 0.f;

  for (int k = 0; k < TOPK_; k++) {
    int c = ip[k];
    float cwk = cwp[k];
    int tok0 = c * CHUNK_;
    // scores  (selected chunks are always fully valid: cs+64 <= sl)
    {
      const float4* krow = (const float4*)(k_cache + (((size_t)b * T_ + tok0 + t) * HKV_ + kvh) * HD_);
      const float4* qp4 = (const float4*)qs;
      float part = 0.f;
#pragma unroll
      for (int i = 0; i < 8; i++) {
        float4 k4 = krow[q4 * 8 + i];
        float4 qv = qp4[q4 * 8 + i];
        part += k4.x * qv.x + k4.y * qv.y + k4.z * qv.z + k4.w * qv.w;
      }
      part += __shfl_xor(part, 1);
      part += __shfl_xor(part, 2);
      if (q4 == 0) pS[t] = part * scale;
    }
    __syncthreads();
    // softmax over 64 tokens (wave 0)
    if (tid < 64) {
      float s = pS[tid];
      float m = s;
#pragma unroll
      for (int off = 1; off < 64; off <<= 1) m = fmaxf(m, __shfl_xor(m, off));
      float e2 = expf(s - m);
      float sum = e2;
#pragma unroll
      for (int off = 1; off < 64; off <<= 1) sum += __shfl_xor(sum, off);
      pS[tid] = e2 / sum;
    }
    __syncthreads();
    // PV
    {
      const float* vbase = v_cache + (((size_t)b * T_ + tok0) * HKV_ + kvh) * HD_ + d;
      float tmp = 0.f;
      int tstart = tp * 32;
#pragma unroll 8
      for (int tt = tstart; tt < tstart + 32; tt++) {
        tmp += pS[tt] * vbase[(size_t)tt * (HKV_ * HD_)];
      }
      acc += cwk * tmp;
    }
    __syncthreads();
  }
  // combine token halves + SWA branch
  if (tp == 1) accS[d] = acc;
  __syncthreads();
  if (tp == 0) {
    float cw16 = cwp[TOPK_];
    float o = acc + accS[d] + qs[d] * cw16;
    o_mid[(size_t)bh * HD_ + d] = o;
  }
}

extern "C" void kernel_launch(void* const* d_in, const int* in_sizes, int n_in,
                              void* d_out, int out_size, void* d_ws, size_t ws_size,
                              hipStream_t stream)
{
  const float* hidden  = (const float*)d_in[0];
  const float* k_cache = (const float*)d_in[1];
  const float* v_cache = (const float*)d_in[2];
  const float* lse_swa = (const float*)d_in[3];
  const float* Wq      = (const float*)d_in[4];
  const float* bq      = (const float*)d_in[5];
  const float* Wo      = (const float*)d_in[6];
  const float* bo      = (const float*)d_in[7];
  const float* qn_w    = (const float*)d_in[8];
  const float* lmkn_w  = (const float*)d_in[9];
  const int*   seq_lens = (const int*)d_in[10];
  float* out = (float*)d_out;

  float* q_raw  = (float*)d_ws;                       // 16*32*128
  float* q_norm = q_raw + B_ * HQ_ * HD_;
  float* o_mid  = q_norm + B_ * HQ_ * HD_;
  float* cw_ws  = o_mid + B_ * HQ_ * HD_;             // 16*32*17
  int*   idx_ws = (int*)(cw_ws + B_ * HQ_ * (TOPK_ + 1));

  hipMemsetAsync(q_raw, 0, B_ * DM_ * sizeof(float), stream);
  hipMemsetAsync(d_out, 0, B_ * DM_ * sizeof(float), stream);

  dim3 gg(DM_ / 256, SPLITK);
  gemm16_splitk<<<gg, 256, 0, stream>>>(hidden, Wq, bq, q_raw);
  lmk_topk_kernel<<<B_ * HKV_, 256, 0, stream>>>(q_raw, k_cache, lse_swa, qn_w,
                                                 lmkn_w, seq_lens, q_norm, cw_ws, idx_ws);
  attn_kernel<<<B_ * HQ_, 256, 0, stream>>>(q_norm, k_cache, v_cache, cw_ws, idx_ws, o_mid);
  gemm16_splitk<<<gg, 256, 0, stream>>>(o_mid, Wo, bo, out);
}

// Round 2
// 693.180 us; speedup vs baseline: 1.1002x; 1.1002x over previous
//
#include <hip/hip_runtime.h>
#include <hip/hip_bf16.h>

#define B_ 16
#define T_ 4096
#define HKV_ 8
#define HD_ 128
#define DM_ 4096
#define HQ_ 32
#define G_ 4
#define CHUNK_ 64
#define TOPK_ 16
#define WINDOW_ 512
#define NC_ 64
#define EPS_ 1e-6f

#define SPLITK 32
#define KCH (DM_ / SPLITK)   // 128

// ---------------- GEMM stage 1: partials[ky][b][n] = sum_{k in slice} A[b,k]*W[k,n] ----------------
__global__ __launch_bounds__(256) void gemm16_partial(
    const float* __restrict__ A, const float* __restrict__ W, float* __restrict__ P)
{
  int n = blockIdx.x * 256 + threadIdx.x;
  int k0 = blockIdx.y * KCH;
  float acc[B_];
#pragma unroll
  for (int b = 0; b < B_; b++) acc[b] = 0.f;
  const float* Wp = W + (size_t)k0 * DM_ + n;
  const float* Ap = A + k0;
#pragma unroll 8
  for (int kk = 0; kk < KCH; kk++) {
    float w = Wp[(size_t)kk * DM_];
#pragma unroll
    for (int b = 0; b < B_; b++) acc[b] += Ap[b * DM_ + kk] * w;
  }
  float* Pp = P + ((size_t)blockIdx.y * B_) * DM_ + n;
#pragma unroll
  for (int b = 0; b < B_; b++) Pp[(size_t)b * DM_] = acc[b];
}

// ---------------- GEMM stage 2: C[b,n] = bias[n] + sum_ky P[ky][b][n] ----------------
__global__ __launch_bounds__(256) void gemm16_reduce(
    const float* __restrict__ P, const float* __restrict__ bias, float* __restrict__ C)
{
  int i = blockIdx.x * 256 + threadIdx.x;   // over 16*4096
  int b = i >> 12, n = i & (DM_ - 1);
  float s = bias[n];
#pragma unroll
  for (int ky = 0; ky < SPLITK; ky++) s += P[(size_t)(ky * B_ + b) * DM_ + n];
  C[i] = s;
}

// ---------------- landmarks + scores + top-16 + chunk weights ----------------
// grid: B*HKV blocks, 1024 threads (16 waves)
__global__ __launch_bounds__(1024) void lmk_topk_kernel(
    const float* __restrict__ q_raw, const float* __restrict__ k_cache,
    const float* __restrict__ lse_swa, const float* __restrict__ qn_w,
    const float* __restrict__ lmkn_w, const int* __restrict__ seq_lens,
    float* __restrict__ q_norm, float* __restrict__ cw_ws, int* __restrict__ idx_ws)
{
  int blk = blockIdx.x;
  int b = blk / HKV_, kv = blk % HKV_;
  int tid = threadIdx.x;
  int w = tid >> 6, lane = tid & 63;
  int d0 = lane * 2;

  __shared__ float qs[G_][HD_];
  __shared__ float sS[G_][NC_];

  const float scale = 0.088388347648318447f;  // 1/sqrt(128)
  float lw0 = lmkn_w[d0], lw1 = lmkn_w[d0 + 1];

  // phase 1: each wave normalizes 4 landmarks (c = w + 16j); waves 0-3 also q-RMSNorm
  float l0[4], l1[4];
#pragma unroll
  for (int j = 0; j < 4; j++) {
    int c = w + 16 * j;
    const float2* kp = (const float2*)(k_cache + (((size_t)b * T_ + c * CHUNK_) * HKV_ + kv) * HD_);
    float2 v = kp[lane];
    float ss = v.x * v.x + v.y * v.y;
#pragma unroll
    for (int off = 1; off < 64; off <<= 1) ss += __shfl_xor(ss, off);
    float rs = rsqrtf(ss * (1.0f / HD_) + EPS_);
    l0[j] = v.x * rs * lw0;
    l1[j] = v.y * rs * lw1;
  }
  if (w < G_) {
    int qh = kv * G_ + w;
    const float* qp = q_raw + ((size_t)b * HQ_ + qh) * HD_;
    float v0 = qp[d0], v1 = qp[d0 + 1];
    float ss = v0 * v0 + v1 * v1;
#pragma unroll
    for (int off = 1; off < 64; off <<= 1) ss += __shfl_xor(ss, off);
    float rs = rsqrtf(ss * (1.0f / HD_) + EPS_);
    float n0 = v0 * rs * qn_w[d0], n1 = v1 * rs * qn_w[d0 + 1];
    qs[w][d0] = n0; qs[w][d0 + 1] = n1;
    float* qo = q_norm + ((size_t)b * HQ_ + qh) * HD_;
    qo[d0] = n0; qo[d0 + 1] = n1;
  }
  __syncthreads();

  // phase 2: dots vs the 4 q heads
#pragma unroll
  for (int j = 0; j < 4; j++) {
    int c = w + 16 * j;
#pragma unroll
    for (int gi = 0; gi < G_; gi++) {
      float p = l0[j] * qs[gi][d0] + l1[j] * qs[gi][d0 + 1];
#pragma unroll
      for (int off = 1; off < 64; off <<= 1) p += __shfl_xor(p, off);
      if (lane == 0) sS[gi][c] = p * scale;
    }
  }
  __syncthreads();

  // phase 3: validity + top-16 + softmax([scores, lse]); waves 0-3, wave w = head w
  if (w < G_) {
    int qh = kv * G_ + w;
    int sl = seq_lens[b];
    int cs = lane * CHUNK_;
    float s = sS[w][lane];
    bool valid = (cs + CHUNK_ <= sl) && (cs < sl - WINDOW_);
    if (!valid) s = -1e9f;

    float topv[TOPK_]; int topi[TOPK_];
    float cur = s;
    for (int j = 0; j < TOPK_; j++) {
      float v = cur; int ix = lane;
#pragma unroll
      for (int off = 1; off < 64; off <<= 1) {
        float ov = __shfl_xor(v, off);
        int oi = __shfl_xor(ix, off);
        if (ov > v || (ov == v && oi < ix)) { v = ov; ix = oi; }
      }
      topv[j] = v; topi[j] = ix;
      if (lane == ix) cur = -INFINITY;
    }

    float lse = lse_swa[b * HQ_ + qh];
    float m = lse;
#pragma unroll
    for (int j = 0; j < TOPK_; j++) m = fmaxf(m, topv[j]);
    float sum = expf(lse - m);
    float e[TOPK_];
#pragma unroll
    for (int j = 0; j < TOPK_; j++) { e[j] = expf(topv[j] - m); sum += e[j]; }
    float inv = 1.0f / sum;
    if (lane == 0) {
      float* cwp = cw_ws + ((size_t)b * HQ_ + qh) * (TOPK_ + 1);
      int* ip = idx_ws + ((size_t)b * HQ_ + qh) * TOPK_;
#pragma unroll
      for (int j = 0; j < TOPK_; j++) { cwp[j] = e[j] * inv; ip[j] = topi[j]; }
      cwp[TOPK_] = expf(lse - m) * inv;
    }
  }
}

// ---------------- per-chunk softmax attention, one chunk per block ----------------
// grid: B*HQ*TOPK = 8192 blocks, 256 threads
__global__ __launch_bounds__(256) void attn_chunk(
    const float* __restrict__ q_norm, const float* __restrict__ k_cache,
    const float* __restrict__ v_cache, const float* __restrict__ cw_ws,
    const int* __restrict__ idx_ws, float* __restrict__ part_o)
{
  int blk = blockIdx.x;
  int bh = blk >> 4, k = blk & (TOPK_ - 1);
  int b = bh >> 5, h = bh & 31;
  int kvh = h >> 2;
  int tid = threadIdx.x;

  __shared__ float qs[HD_];
  __shared__ float pS[CHUNK_];
  __shared__ float Vs[CHUNK_][HD_];
  __shared__ float accS[HD_];

  int c = idx_ws[bh * TOPK_ + k];
  float cwk = cw_ws[bh * (TOPK_ + 1) + k];
  int tok0 = c * CHUNK_;
  const float* Kbase = k_cache + (((size_t)b * T_ + tok0) * HKV_ + kvh) * HD_;
  const float* Vbase = v_cache + (((size_t)b * T_ + tok0) * HKV_ + kvh) * HD_;
  const int rowstride = HKV_ * HD_;   // 1024 floats between tokens

  if (tid < HD_) qs[tid] = q_norm[(size_t)bh * HD_ + tid];

  // prefetch V chunk into registers (in flight during score phase)
  float4 vreg[8];
#pragma unroll
  for (int i = 0; i < 8; i++) {
    int f = i * 256 + tid;          // float4 index in [64 x 32]
    int tok = f >> 5, d4 = f & 31;
    vreg[i] = *(const float4*)(Vbase + (size_t)tok * rowstride + d4 * 4);
  }
  __syncthreads();  // qs ready

  // scores: token t (64) x dim-quarter q4 (4)
  {
    int t = tid >> 2, q4 = tid & 3;
    const float4* krow = (const float4*)(Kbase + (size_t)t * rowstride);
    const float4* qp4 = (const float4*)qs;
    float part = 0.f;
#pragma unroll
    for (int i = 0; i < 8; i++) {
      float4 k4 = krow[q4 * 8 + i];
      float4 qv = qp4[q4 * 8 + i];
      part += k4.x * qv.x + k4.y * qv.y + k4.z * qv.z + k4.w * qv.w;
    }
    part += __shfl_xor(part, 1);
    part += __shfl_xor(part, 2);
    if (q4 == 0) pS[t] = part * 0.088388347648318447f;
  }
  // V registers -> LDS
#pragma unroll
  for (int i = 0; i < 8; i++) {
    int f = i * 256 + tid;
    int tok = f >> 5, d4 = f & 31;
    *(float4*)&Vs[tok][d4 * 4] = vreg[i];
  }
  __syncthreads();

  // softmax over 64 tokens (wave 0); selected chunks are always fully valid
  if (tid < 64) {
    float s = pS[tid];
    float m = s;
#pragma unroll
    for (int off = 1; off < 64; off <<= 1) m = fmaxf(m, __shfl_xor(m, off));
    float e2 = expf(s - m);
    float sum = e2;
#pragma unroll
    for (int off = 1; off < 64; off <<= 1) sum += __shfl_xor(sum, off);
    pS[tid] = e2 / sum;
  }
  __syncthreads();

  // PV from LDS: dim d (128) x token-half tp (2)
  {
    int d = tid & 127, tp = tid >> 7;
    float acc = 0.f;
#pragma unroll
    for (int tt = 0; tt < 32; tt++) acc += pS[tp * 32 + tt] * Vs[tp * 32 + tt][d];
    if (tp) accS[d] = acc;
    __syncthreads();
    if (!tp) part_o[((size_t)bh * TOPK_ + k) * HD_ + d] = cwk * (acc + accS[d]);
  }
}

// ---------------- combine chunk partials + SWA branch ----------------
// grid: B*HQ blocks, 128 threads
__global__ __launch_bounds__(128) void combine_kernel(
    const float* __restrict__ part_o, const float* __restrict__ q_norm,
    const float* __restrict__ cw_ws, float* __restrict__ o_mid)
{
  int bh = blockIdx.x;
  int d = threadIdx.x;
  float s = 0.f;
#pragma unroll
  for (int k = 0; k < TOPK_; k++) s += part_o[((size_t)bh * TOPK_ + k) * HD_ + d];
  s += q_norm[(size_t)bh * HD_ + d] * cw_ws[bh * (TOPK_ + 1) + TOPK_];
  o_mid[(size_t)bh * HD_ + d] = s;
}

extern "C" void kernel_launch(void* const* d_in, const int* in_sizes, int n_in,
                              void* d_out, int out_size, void* d_ws, size_t ws_size,
                              hipStream_t stream)
{
  const float* hidden  = (const float*)d_in[0];
  const float* k_cache = (const float*)d_in[1];
  const float* v_cache = (const float*)d_in[2];
  const float* lse_swa = (const float*)d_in[3];
  const float* Wq      = (const float*)d_in[4];
  const float* bq      = (const float*)d_in[5];
  const float* Wo      = (const float*)d_in[6];
  const float* bo      = (const float*)d_in[7];
  const float* qn_w    = (const float*)d_in[8];
  const float* lmkn_w  = (const float*)d_in[9];
  const int*   seq_lens = (const int*)d_in[10];
  float* out = (float*)d_out;

  float* part1  = (float*)d_ws;                          // 32*16*4096   = 2M floats
  float* part_o = part1 + (size_t)SPLITK * B_ * DM_;     // 16*32*16*128 = 1M floats
  float* q_raw  = part_o + (size_t)B_ * HQ_ * TOPK_ * HD_;
  float* q_norm = q_raw + B_ * DM_;
  float* o_mid  = q_norm + B_ * DM_;
  float* cw_ws  = o_mid + B_ * DM_;                      // 16*32*17
  int*   idx_ws = (int*)(cw_ws + B_ * HQ_ * (TOPK_ + 1));

  dim3 gg(DM_ / 256, SPLITK);
  gemm16_partial<<<gg, 256, 0, stream>>>(hidden, Wq, part1);
  gemm16_reduce<<<B_ * DM_ / 256, 256, 0, stream>>>(part1, bq, q_raw);
  lmk_topk_kernel<<<B_ * HKV_, 1024, 0, stream>>>(q_raw, k_cache, lse_swa, qn_w,
                                                  lmkn_w, seq_lens, q_norm, cw_ws, idx_ws);
  attn_chunk<<<B_ * HQ_ * TOPK_, 256, 0, stream>>>(q_norm, k_cache, v_cache, cw_ws, idx_ws, part_o);
  combine_kernel<<<B_ * HQ_, 128, 0, stream>>>(part_o, q_norm, cw_ws, o_mid);
  gemm16_partial<<<gg, 256, 0, stream>>>(o_mid, Wo, part1);
  gemm16_reduce<<<B_ * DM_ / 256, 256, 0, stream>>>(part1, bo, out);
}